// Round 4
// baseline (1101.133 us; speedup 1.0000x reference)
//
#include <hip/hip_runtime.h>
#include <hip/hip_bf16.h>

typedef __hip_bfloat16 bf16;
typedef __attribute__((ext_vector_type(8))) short short8;
typedef __attribute__((ext_vector_type(4))) float f32x4;

#define HDIM 512
#define SLOPE 0.01f
#define BN_EPS 1e-5f

__device__ inline float bf2f(short s) {
    unsigned u = ((unsigned)(unsigned short)s) << 16;
    return __builtin_bit_cast(float, u);
}

// ---------------- runtime dtype detection ----------------
// flags[0]=1 if indices are int64; flags[1]=1 if float tensors are fp32.
// int64 test: values < 2^31 => high int32 words all zero.
// fp32 test: low 16 bits of fp32 words are mantissa noise -> decoded as bf16
// they rarely (~6%) land in [9e-4, 64]; genuine bf16 data lands there ~99.9%.
__global__ void detect_types(const int* __restrict__ ei, const unsigned* __restrict__ xw,
                             int* __restrict__ flags) {
    __shared__ int nzhi, okbf;
    if (threadIdx.x == 0) { nzhi = 0; okbf = 0; }
    __syncthreads();
    int lo = 0, ok = 0;
    for (int i = threadIdx.x; i < 2048; i += 256)
        if (ei[2 * i + 1] != 0) lo++;
    for (int i = threadIdx.x; i < 1024; i += 256) {
        unsigned w = (xw[i] & 0xFFFFu) << 16;
        float av = fabsf(__builtin_bit_cast(float, w));
        if (av > 0.0009f && av < 64.0f) ok++;
    }
    if (lo) atomicAdd(&nzhi, lo);
    if (ok) atomicAdd(&okbf, ok);
    __syncthreads();
    if (threadIdx.x == 0) {
        flags[0] = (nzhi == 0) ? 1 : 0;   // 1 => int64 indices
        flags[1] = (okbf < 512) ? 1 : 0;  // 1 => fp32 floats
    }
}

__global__ void conv_idx(const int* __restrict__ src, int* __restrict__ dst, int n,
                         const int* __restrict__ flags) {
    int i = blockIdx.x * blockDim.x + threadIdx.x;
    if (i < n) dst[i] = flags[0] ? (int)((const long long*)src)[i] : src[i];
}

__global__ void conv_float(const void* __restrict__ src, bf16* __restrict__ dst, int n,
                           const int* __restrict__ flags) {
    int i = blockIdx.x * blockDim.x + threadIdx.x;
    if (i < n)
        dst[i] = flags[1] ? __float2bfloat16(((const float*)src)[i])
                          : ((const bf16*)src)[i];
}

// ---------------- degree + CSR build ----------------
__global__ void count_deg(const int* __restrict__ col, int* __restrict__ cnt, int e) {
    int i = blockIdx.x * blockDim.x + threadIdx.x;
    if (i < e) atomicAdd(&cnt[col[i]], 1);
}

__global__ void finalize_deg(const int* __restrict__ cnt, float* __restrict__ dinv,
                             float* __restrict__ selfw, int n) {
    int i = blockIdx.x * blockDim.x + threadIdx.x;
    if (i < n) {
        float d = (float)cnt[i] + 2.0f;   // improved=True self weight
        dinv[i] = rsqrtf(d);
        selfw[i] = 2.0f / d;              // SELF_W * dinv^2
    }
}

#define SCAN_T 1024
__global__ __launch_bounds__(1024) void scan_offsets(
    const int* __restrict__ counts, int* __restrict__ offsets, int n, int e)
{
    __shared__ int s[SCAN_T];
    int t = threadIdx.x;
    int chunk = (n + SCAN_T - 1) / SCAN_T;
    int i0 = t * chunk;
    int i1 = min(i0 + chunk, n);
    int local = 0;
    for (int i = i0; i < i1; i++) local += counts[i];
    s[t] = local;
    __syncthreads();
    for (int off = 1; off < SCAN_T; off <<= 1) {
        int v = (t >= off) ? s[t - off] : 0;
        __syncthreads();
        s[t] += v;
        __syncthreads();
    }
    int running = (t == 0) ? 0 : s[t - 1];
    for (int i = i0; i < i1; i++) { offsets[i] = running; running += counts[i]; }
    if (t == SCAN_T - 1) offsets[n] = e;
}

__global__ void scatter_edges(const int* __restrict__ rows, const int* __restrict__ cols,
                              const int* __restrict__ offsets, int* __restrict__ cursor,
                              int* __restrict__ src, int e)
{
    int i = blockIdx.x * blockDim.x + threadIdx.x;
    if (i < e) {
        int d = cols[i];
        int pos = offsets[d] + atomicAdd(&cursor[d], 1);
        src[pos] = rows[i];
    }
}

// ---------------- GEMM: C[M,N] = A[M,K] @ B[K,N] (+bias), fp32 acc --------------
// A: bf16, or fp32 when (af32 && *af32). C: bf16, or fp32 when (cf32 && *cf32).
#define BM 128
#define BNT 64
#define BKT 32
#define LDSP (BKT + 8)

__global__ __launch_bounds__(256) void gemm_bf16(
    const void* __restrict__ A, const bf16* __restrict__ B,
    void* __restrict__ C, const bf16* __restrict__ bias,
    int M, int K, int N,
    const int* __restrict__ af32, const int* __restrict__ cf32)
{
    __shared__ bf16 As[BM][LDSP];
    __shared__ bf16 Bs[BNT][LDSP];   // transposed: [n][k]

    bool a32 = af32 && *af32;
    bool c32 = cf32 && *cf32;

    int tid = threadIdx.x;
    int wave = tid >> 6;
    int lane = tid & 63;
    int q = lane >> 4;
    int r = lane & 15;
    int wm = (wave >> 1) * 64;
    int wn = (wave & 1) * 32;
    int m0 = blockIdx.y * BM;
    int n0 = blockIdx.x * BNT;

    f32x4 acc[4][2];
#pragma unroll
    for (int mi = 0; mi < 4; mi++)
#pragma unroll
        for (int ni = 0; ni < 2; ni++)
            acc[mi][ni] = {0.f, 0.f, 0.f, 0.f};

    for (int k0 = 0; k0 < K; k0 += BKT) {
#pragma unroll
        for (int i = 0; i < 2; i++) {
            int rr = (tid >> 2) + i * 64;
            int kk = (tid & 3) * 8;
            int gm = m0 + rr;
            short8 v = {0, 0, 0, 0, 0, 0, 0, 0};
            if (gm < M) {
                if (a32) {
                    const float* Af = (const float*)A + (size_t)gm * K + (k0 + kk);
#pragma unroll
                    for (int j = 0; j < 8; j++)
                        ((bf16*)&v)[j] = __float2bfloat16(Af[j]);
                } else {
                    v = *(const short8*)((const bf16*)A + (size_t)gm * K + (k0 + kk));
                }
            }
            *(short8*)&As[rr][kk] = v;
        }
        {
            int kk = tid >> 3;
            int nn = (tid & 7) * 8;
            short8 v = *(const short8*)(B + (size_t)(k0 + kk) * N + (n0 + nn));
#pragma unroll
            for (int j = 0; j < 8; j++) *(short*)&Bs[nn + j][kk] = v[j];
        }
        __syncthreads();

        short8 a[4], b[2];
#pragma unroll
        for (int mi = 0; mi < 4; mi++) a[mi] = *(const short8*)&As[wm + mi * 16 + r][q * 8];
#pragma unroll
        for (int ni = 0; ni < 2; ni++) b[ni] = *(const short8*)&Bs[wn + ni * 16 + r][q * 8];
#pragma unroll
        for (int mi = 0; mi < 4; mi++)
#pragma unroll
            for (int ni = 0; ni < 2; ni++)
                acc[mi][ni] = __builtin_amdgcn_mfma_f32_16x16x32_bf16(a[mi], b[ni], acc[mi][ni], 0, 0, 0);
        __syncthreads();
    }

#pragma unroll
    for (int mi = 0; mi < 4; mi++) {
#pragma unroll
        for (int ni = 0; ni < 2; ni++) {
            int gn = n0 + wn + ni * 16 + r;
            float bv = bias ? __bfloat162float(bias[gn]) : 0.f;
#pragma unroll
            for (int reg = 0; reg < 4; reg++) {
                int gm = m0 + wm + mi * 16 + q * 4 + reg;
                if (gm < M) {
                    float val = acc[mi][ni][reg] + bv;
                    if (c32) ((float*)C)[(size_t)gm * N + gn] = val;
                    else     ((bf16*)C)[(size_t)gm * N + gn] = __float2bfloat16(val);
                }
            }
        }
    }
}

// ---------------- CSR edge aggregation: y[d] = selfw[d]*h[d] + sum norm*h[src] ----
__global__ __launch_bounds__(256) void agg_csr(
    const bf16* __restrict__ h, const int* __restrict__ offsets,
    const int* __restrict__ src, const float* __restrict__ dinv,
    const float* __restrict__ selfw, bf16* __restrict__ y, int n)
{
    int wave = threadIdx.x >> 6;
    int lane = threadIdx.x & 63;
    int dst = blockIdx.x * 4 + wave;
    if (dst >= n) return;
    int s0 = offsets[dst];
    int s1 = offsets[dst + 1];
    float di = dinv[dst];
    float sw = selfw[dst];
    short8 hv = *(const short8*)(h + (size_t)dst * HDIM + lane * 8);
    float acc[8];
#pragma unroll
    for (int j = 0; j < 8; j++) acc[j] = sw * bf2f(hv[j]);
    for (int p = s0; p < s1; p++) {
        int sr = src[p];
        float norm = di * dinv[sr];
        short8 v = *(const short8*)(h + (size_t)sr * HDIM + lane * 8);
#pragma unroll
        for (int j = 0; j < 8; j++) acc[j] += norm * bf2f(v[j]);
    }
    short8 o;
#pragma unroll
    for (int j = 0; j < 8; j++) ((bf16*)&o)[j] = __float2bfloat16(acc[j]);
    *(short8*)(y + (size_t)dst * HDIM + lane * 8) = o;
}

// ---------------- BatchNorm (training stats) + LeakyReLU ------------------------
__global__ __launch_bounds__(512) void bn_stats(
    const bf16* __restrict__ y, float* __restrict__ gsum, float* __restrict__ gsq, int n)
{
    int f = threadIdx.x;   // 512 threads = one feature each
    int per = (n + gridDim.x - 1) / gridDim.x;
    int r0 = blockIdx.x * per;
    int r1 = min(r0 + per, n);
    float s = 0.f, sq = 0.f;
    for (int rr = r0; rr < r1; rr++) {
        float v = bf2f(__builtin_bit_cast(short, y[(size_t)rr * HDIM + f]));
        s += v; sq += v * v;
    }
    atomicAdd(&gsum[f], s);
    atomicAdd(&gsq[f], sq);
}

__global__ void bn_final(const float* __restrict__ gsum, const float* __restrict__ gsq,
                         const bf16* __restrict__ gamma, const bf16* __restrict__ beta,
                         float* __restrict__ scale, float* __restrict__ shift, float invN)
{
    int f = threadIdx.x;
    float mu = gsum[f] * invN;
    float var = fmaxf(gsq[f] * invN - mu * mu, 0.f);
    float inv = rsqrtf(var + BN_EPS);
    float sc = __bfloat162float(gamma[f]) * inv;
    scale[f] = sc;
    shift[f] = __bfloat162float(beta[f]) - mu * sc;
}

__global__ __launch_bounds__(256) void bn_apply(
    bf16* __restrict__ y, const float* __restrict__ scale,
    const float* __restrict__ shift, long long total8)
{
    long long idx = (long long)blockIdx.x * 256 + threadIdx.x;
    if (idx >= total8) return;
    int f0 = (int)((idx * 8) & (HDIM - 1));
    short8 v = *(const short8*)((const bf16*)y + idx * 8);
    short8 o;
#pragma unroll
    for (int j = 0; j < 8; j++) {
        float val = scale[f0 + j] * bf2f(v[j]) + shift[f0 + j];
        ((bf16*)&o)[j] = __float2bfloat16(val > 0.f ? val : SLOPE * val);
    }
    *(short8*)(y + idx * 8) = o;
}

// ---------------- segment-max pooling over sorted batch --------------------------
__global__ __launch_bounds__(512) void pool_max(
    const bf16* __restrict__ h, const int* __restrict__ batch,
    bf16* __restrict__ pooled, int n)
{
    int g = blockIdx.x;
    int f = threadIdx.x;
    int lo = 0, hi = n;
    while (lo < hi) { int mid = (lo + hi) >> 1; if (batch[mid] < g) lo = mid + 1; else hi = mid; }
    int s = lo;
    hi = n;
    while (lo < hi) { int mid = (lo + hi) >> 1; if (batch[mid] <= g) lo = mid + 1; else hi = mid; }
    int e = lo;
    float m = -3.0e38f;
    for (int rr = s; rr < e; rr++)
        m = fmaxf(m, bf2f(__builtin_bit_cast(short, h[(size_t)rr * HDIM + f])));
    pooled[(size_t)g * HDIM + f] = __float2bfloat16(s < e ? m : 0.f);
}

// ---------------- orchestration --------------------------------------------------
extern "C" void kernel_launch(void* const* d_in, const int* in_sizes, int n_in,
                              void* d_out, int out_size, void* d_ws, size_t ws_size,
                              hipStream_t stream)
{
    const void* x     = d_in[0];
    const int*  ei    = (const int*)d_in[1];
    const int*  batch = (const int*)d_in[2];
    // d_in[4]=b1, d_in[8]=b2 cancel exactly in training-mode BatchNorm — unused.

    const int N   = in_sizes[2];
    const int E   = in_sizes[1] / 2;
    const int DIN = in_sizes[0] / N;
    const int OUT = in_sizes[12];
    const int G   = out_size / OUT;

    // workspace carve — ~220 MB total
    char* p = (char*)d_ws;
    bf16* buf1   = (bf16*)p;  p += (size_t)N * HDIM * sizeof(bf16);   // 102.4 MB
    bf16* buf2   = (bf16*)p;  p += (size_t)N * HDIM * sizeof(bf16);   // 102.4 MB
    bf16* pooled = (bf16*)p;  p += (size_t)G * HDIM * sizeof(bf16);   // 4.2 MB
    bf16* w1bf   = (bf16*)p;  p += (size_t)DIN * HDIM * sizeof(bf16);
    bf16* w2bf   = (bf16*)p;  p += (size_t)HDIM * HDIM * sizeof(bf16);
    bf16* wfbf   = (bf16*)p;  p += (size_t)HDIM * OUT * sizeof(bf16);
    bf16* g1bf   = (bf16*)p;  p += HDIM * sizeof(bf16);
    bf16* be1bf  = (bf16*)p;  p += HDIM * sizeof(bf16);
    bf16* g2bf   = (bf16*)p;  p += HDIM * sizeof(bf16);
    bf16* be2bf  = (bf16*)p;  p += HDIM * sizeof(bf16);
    bf16* bfbf   = (bf16*)p;  p += ((OUT + 8) & ~7) * sizeof(bf16);
    int* ei32    = (int*)p;   p += (size_t)2 * E * sizeof(int);
    int* batch32 = (int*)p;   p += (size_t)N * sizeof(int);
    float* dinv  = (float*)p; p += (size_t)N * sizeof(float);
    float* selfw = (float*)p; p += (size_t)N * sizeof(float);
    int* offsets = (int*)p;   p += (size_t)(N + 4) * sizeof(int);
    int* cursor  = (int*)p;   p += (size_t)N * sizeof(int);
    int* srcarr  = (int*)p;   p += (size_t)E * sizeof(int);
    float* gsum  = (float*)p; p += HDIM * sizeof(float);
    float* gsq   = (float*)p; p += HDIM * sizeof(float);
    float* scale = (float*)p; p += HDIM * sizeof(float);
    float* shift = (float*)p; p += HDIM * sizeof(float);
    int* flags   = (int*)p;   p += 4 * sizeof(int);

    // ---- dtype detection + canonicalization ----
    detect_types<<<1, 256, 0, stream>>>(ei, (const unsigned*)x, flags);
    conv_idx<<<(2 * E + 255) / 256, 256, 0, stream>>>(ei, ei32, 2 * E, flags);
    conv_idx<<<(N + 255) / 256, 256, 0, stream>>>(batch, batch32, N, flags);
    conv_float<<<(DIN * HDIM + 255) / 256, 256, 0, stream>>>(d_in[3], w1bf, DIN * HDIM, flags);
    conv_float<<<(HDIM * HDIM + 255) / 256, 256, 0, stream>>>(d_in[7], w2bf, HDIM * HDIM, flags);
    conv_float<<<(HDIM * OUT + 255) / 256, 256, 0, stream>>>(d_in[11], wfbf, HDIM * OUT, flags);
    conv_float<<<2, 256, 0, stream>>>(d_in[5], g1bf, HDIM, flags);
    conv_float<<<2, 256, 0, stream>>>(d_in[6], be1bf, HDIM, flags);
    conv_float<<<2, 256, 0, stream>>>(d_in[9], g2bf, HDIM, flags);
    conv_float<<<2, 256, 0, stream>>>(d_in[10], be2bf, HDIM, flags);
    conv_float<<<1, 256, 0, stream>>>(d_in[12], bfbf, OUT, flags);

    const int* rows = ei32;
    const int* cols = ei32 + E;

    // CSR + degree (shared by both conv layers)
    hipMemsetAsync(cursor, 0, (size_t)N * sizeof(int), stream);
    count_deg<<<(E + 255) / 256, 256, 0, stream>>>(cols, cursor, E);
    finalize_deg<<<(N + 255) / 256, 256, 0, stream>>>(cursor, dinv, selfw, N);
    scan_offsets<<<1, SCAN_T, 0, stream>>>(cursor, offsets, N, E);
    hipMemsetAsync(cursor, 0, (size_t)N * sizeof(int), stream);
    scatter_edges<<<(E + 255) / 256, 256, 0, stream>>>(rows, cols, offsets, cursor, srcarr, E);

    dim3 gemm_grid1(HDIM / BNT, (N + BM - 1) / BM);
    long long tot8 = (long long)N * HDIM / 8;
    int agg_blocks = (N + 3) / 4;

    // ---- layer 1 ----
    gemm_bf16<<<gemm_grid1, 256, 0, stream>>>(x, w1bf, buf1, nullptr, N, DIN, HDIM,
                                              flags + 1, nullptr);
    agg_csr<<<agg_blocks, 256, 0, stream>>>(buf1, offsets, srcarr, dinv, selfw, buf2, N);
    hipMemsetAsync(gsum, 0, 2 * HDIM * sizeof(float), stream);   // gsum+gsq contiguous
    bn_stats<<<256, HDIM, 0, stream>>>(buf2, gsum, gsq, N);
    bn_final<<<1, HDIM, 0, stream>>>(gsum, gsq, g1bf, be1bf, scale, shift, 1.0f / N);
    bn_apply<<<(int)((tot8 + 255) / 256), 256, 0, stream>>>(buf2, scale, shift, tot8);

    // ---- layer 2 ----
    gemm_bf16<<<gemm_grid1, 256, 0, stream>>>(buf2, w2bf, buf1, nullptr, N, HDIM, HDIM,
                                              nullptr, nullptr);
    agg_csr<<<agg_blocks, 256, 0, stream>>>(buf1, offsets, srcarr, dinv, selfw, buf2, N);
    hipMemsetAsync(gsum, 0, 2 * HDIM * sizeof(float), stream);
    bn_stats<<<256, HDIM, 0, stream>>>(buf2, gsum, gsq, N);
    bn_final<<<1, HDIM, 0, stream>>>(gsum, gsq, g2bf, be2bf, scale, shift, 1.0f / N);
    bn_apply<<<(int)((tot8 + 255) / 256), 256, 0, stream>>>(buf2, scale, shift, tot8);

    // ---- pool + head (output dtype follows input float dtype) ----
    pool_max<<<G, HDIM, 0, stream>>>(buf2, batch32, pooled, N);
    gemm_bf16<<<dim3(OUT / BNT, (G + BM - 1) / BM), 256, 0, stream>>>(
        pooled, wfbf, d_out, bfbf, G, HDIM, OUT, nullptr, flags + 1);
}

// Round 5
// 919.086 us; speedup vs baseline: 1.1981x; 1.1981x over previous
//
#include <hip/hip_runtime.h>
#include <hip/hip_bf16.h>

typedef __hip_bfloat16 bf16;
typedef __attribute__((ext_vector_type(8))) short short8;
typedef __attribute__((ext_vector_type(4))) float f32x4;

#define HDIM 512
#define SLOPE 0.01f
#define BN_EPS 1e-5f

__device__ inline float bf2f(short s) {
    unsigned u = ((unsigned)(unsigned short)s) << 16;
    return __builtin_bit_cast(float, u);
}
__device__ inline unsigned short f2bfbits(float v) {
    bf16 h = __float2bfloat16(v);
    return (unsigned short)__builtin_bit_cast(short, h);
}

// ---------------- runtime dtype detection ----------------
// flags[0]=1 if indices int64; flags[1]=1 if float tensors fp32.
__global__ void detect_types(const int* __restrict__ ei, const unsigned* __restrict__ xw,
                             int* __restrict__ flags) {
    __shared__ int nzhi, okbf;
    if (threadIdx.x == 0) { nzhi = 0; okbf = 0; }
    __syncthreads();
    int lo = 0, ok = 0;
    for (int i = threadIdx.x; i < 2048; i += 256)
        if (ei[2 * i + 1] != 0) lo++;
    for (int i = threadIdx.x; i < 1024; i += 256) {
        unsigned w = (xw[i] & 0xFFFFu) << 16;
        float av = fabsf(__builtin_bit_cast(float, w));
        if (av > 0.0009f && av < 64.0f) ok++;
    }
    if (lo) atomicAdd(&nzhi, lo);
    if (ok) atomicAdd(&okbf, ok);
    __syncthreads();
    if (threadIdx.x == 0) {
        flags[0] = (nzhi == 0) ? 1 : 0;
        flags[1] = (okbf < 512) ? 1 : 0;
    }
}

__global__ void conv_idx(const int* __restrict__ src, int* __restrict__ dst, int n,
                         const int* __restrict__ flags) {
    int i = blockIdx.x * blockDim.x + threadIdx.x;
    if (i < n) dst[i] = flags[0] ? (int)((const long long*)src)[i] : src[i];
}

__global__ void conv_float(const void* __restrict__ src, bf16* __restrict__ dst, int n,
                           const int* __restrict__ flags) {
    int i = blockIdx.x * blockDim.x + threadIdx.x;
    if (i < n)
        dst[i] = flags[1] ? __float2bfloat16(((const float*)src)[i])
                          : ((const bf16*)src)[i];
}

// transpose + convert weight: WT[nn][k] = W[k][nn]  (W is [K][Nn])
__global__ void wt_conv(const void* __restrict__ W, bf16* __restrict__ WT,
                        int K, int Nn, const int* __restrict__ flags) {
    int idx = blockIdx.x * 256 + threadIdx.x;
    if (idx >= K * Nn) return;
    int nn = idx / K;
    int k = idx - nn * K;
    float v = flags[1] ? ((const float*)W)[(size_t)k * Nn + nn]
                       : __bfloat162float(((const bf16*)W)[(size_t)k * Nn + nn]);
    WT[idx] = __float2bfloat16(v);
}

// ---------------- degree + CSR build ----------------
__global__ void count_deg(const int* __restrict__ col, int* __restrict__ cnt, int e) {
    int i = blockIdx.x * blockDim.x + threadIdx.x;
    if (i < e) atomicAdd(&cnt[col[i]], 1);
}

__global__ void finalize_deg(const int* __restrict__ cnt, float* __restrict__ dinv,
                             float* __restrict__ selfw, int n) {
    int i = blockIdx.x * blockDim.x + threadIdx.x;
    if (i < n) {
        float d = (float)cnt[i] + 2.0f;
        dinv[i] = rsqrtf(d);
        selfw[i] = 2.0f / d;
    }
}

#define SCAN_T 1024
__global__ __launch_bounds__(1024) void scan_offsets(
    const int* __restrict__ counts, int* __restrict__ offsets, int n, int e)
{
    __shared__ int s[SCAN_T];
    int t = threadIdx.x;
    int chunk = (n + SCAN_T - 1) / SCAN_T;
    int i0 = t * chunk;
    int i1 = min(i0 + chunk, n);
    int local = 0;
    for (int i = i0; i < i1; i++) local += counts[i];
    s[t] = local;
    __syncthreads();
    for (int off = 1; off < SCAN_T; off <<= 1) {
        int v = (t >= off) ? s[t - off] : 0;
        __syncthreads();
        s[t] += v;
        __syncthreads();
    }
    int running = (t == 0) ? 0 : s[t - 1];
    for (int i = i0; i < i1; i++) { offsets[i] = running; running += counts[i]; }
    if (t == SCAN_T - 1) offsets[n] = e;
}

__global__ void scatter_edges(const int* __restrict__ rows, const int* __restrict__ cols,
                              const int* __restrict__ offsets, int* __restrict__ cursor,
                              int* __restrict__ src, int e)
{
    int i = blockIdx.x * blockDim.x + threadIdx.x;
    if (i < e) {
        int d = cols[i];
        int pos = offsets[d] + atomicAdd(&cursor[d], 1);
        src[pos] = rows[i];
    }
}

// ---------------- full-width GEMM: C[M,NT] = A[M,K] @ BT^T, strips of 64 rows -----
// BT is pre-transposed [NT][K]. APPLY: A-elements get leaky(scale*a+shift) on load.
template<int NT, bool APPLY>
__global__ __launch_bounds__(256, 2) void gemm_nt(
    const bf16* __restrict__ A, const bf16* __restrict__ BT,
    void* __restrict__ C, const bf16* __restrict__ bias,
    const float* __restrict__ scale, const float* __restrict__ shift,
    int M, int K, const int* __restrict__ cf32)
{
    constexpr int NI = NT / 64;          // 16-wide n-tiles per wave
    __shared__ bf16 As[64][40];          // stride 40: frag reads conflict-free
    __shared__ bf16 Bs[NT][40];
    __shared__ float s_sc[APPLY ? HDIM : 1];
    __shared__ float s_sh[APPLY ? HDIM : 1];

    int tid = threadIdx.x;
    int wave = tid >> 6, lane = tid & 63, q = lane >> 4, r = lane & 15;
    int m0 = blockIdx.x * 64;
    int rr = tid >> 2, kk = (tid & 3) * 8;
    bool c32 = cf32 && *cf32;

    if constexpr (APPLY) {
        for (int i = tid; i < K; i += 256) { s_sc[i] = scale[i]; s_sh[i] = shift[i]; }
    }
    __syncthreads();

    f32x4 acc[4][NI];
#pragma unroll
    for (int mi = 0; mi < 4; mi++)
#pragma unroll
        for (int ni = 0; ni < NI; ni++)
            acc[mi][ni] = {0.f, 0.f, 0.f, 0.f};

    int gm = m0 + rr;
    const bf16* Arow = A + (size_t)gm * K + kk;

    for (int k0 = 0; k0 < K; k0 += 32) {
        short8 v = {0, 0, 0, 0, 0, 0, 0, 0};
        if (gm < M) v = *(const short8*)(Arow + k0);
        if constexpr (APPLY) {
            f32x4 sca = *(const f32x4*)&s_sc[k0 + kk];
            f32x4 scb = *(const f32x4*)&s_sc[k0 + kk + 4];
            f32x4 sha = *(const f32x4*)&s_sh[k0 + kk];
            f32x4 shb = *(const f32x4*)&s_sh[k0 + kk + 4];
#pragma unroll
            for (int j = 0; j < 4; j++) {
                float t = sca[j] * bf2f(v[j]) + sha[j];
                v[j] = __builtin_bit_cast(short, (short)f2bfbits(t > 0.f ? t : SLOPE * t));
                float u = scb[j] * bf2f(v[4 + j]) + shb[j];
                v[4 + j] = __builtin_bit_cast(short, (short)f2bfbits(u > 0.f ? u : SLOPE * u));
            }
        }
        *(short8*)&As[rr][kk] = v;
#pragma unroll
        for (int p = 0; p < NT / 64; p++) {
            int n = p * 64 + rr;
            *(short8*)&Bs[n][kk] = *(const short8*)(BT + (size_t)n * K + k0 + kk);
        }
        __syncthreads();

        short8 a[4];
#pragma unroll
        for (int mi = 0; mi < 4; mi++) a[mi] = *(const short8*)&As[mi * 16 + r][q * 8];
#pragma unroll
        for (int ni = 0; ni < NI; ni++) {
            short8 b = *(const short8*)&Bs[wave * (NT / 4) + ni * 16 + r][q * 8];
#pragma unroll
            for (int mi = 0; mi < 4; mi++)
                acc[mi][ni] = __builtin_amdgcn_mfma_f32_16x16x32_bf16(a[mi], b, acc[mi][ni], 0, 0, 0);
        }
        __syncthreads();
    }

#pragma unroll
    for (int mi = 0; mi < 4; mi++) {
#pragma unroll
        for (int ni = 0; ni < NI; ni++) {
            int gn = wave * (NT / 4) + ni * 16 + r;
            float bv = bias ? __bfloat162float(bias[gn]) : 0.f;
#pragma unroll
            for (int reg = 0; reg < 4; reg++) {
                int gm2 = m0 + mi * 16 + q * 4 + reg;
                if (gm2 < M) {
                    float val = acc[mi][ni][reg] + bv;
                    if (c32) ((float*)C)[(size_t)gm2 * NT + gn] = val;
                    else     ((bf16*)C)[(size_t)gm2 * NT + gn] = __float2bfloat16(val);
                }
            }
        }
    }
}

// ---------------- CSR aggregation, 128-dim input (fp32 or bf16 x) -----------------
__global__ __launch_bounds__(256) void agg_csr_din(
    const void* __restrict__ x, const int* __restrict__ offsets,
    const int* __restrict__ src, const float* __restrict__ dinv,
    const float* __restrict__ selfw, bf16* __restrict__ out,
    int n, const int* __restrict__ flags)
{
    int wave = threadIdx.x >> 6, lane = threadIdx.x & 63;
    int dst = blockIdx.x * 4 + wave;
    if (dst >= n) return;
    bool f32 = flags[1] != 0;
    int s0 = offsets[dst], s1 = offsets[dst + 1];
    float di = dinv[dst], sw = selfw[dst];
    float a0, a1;
    if (f32) {
        float2 v = ((const float2*)x)[(size_t)dst * 64 + lane];
        a0 = sw * v.x; a1 = sw * v.y;
    } else {
        unsigned u = ((const unsigned*)x)[(size_t)dst * 64 + lane];
        a0 = sw * bf2f((short)(u & 0xFFFF)); a1 = sw * bf2f((short)(u >> 16));
    }
    for (int p = s0; p < s1; p++) {
        int sr = src[p];
        float nm = di * dinv[sr];
        if (f32) {
            float2 v = ((const float2*)x)[(size_t)sr * 64 + lane];
            a0 += nm * v.x; a1 += nm * v.y;
        } else {
            unsigned u = ((const unsigned*)x)[(size_t)sr * 64 + lane];
            a0 += nm * bf2f((short)(u & 0xFFFF)); a1 += nm * bf2f((short)(u >> 16));
        }
    }
    unsigned o = (unsigned)f2bfbits(a0) | ((unsigned)f2bfbits(a1) << 16);
    ((unsigned*)out)[(size_t)dst * 64 + lane] = o;
}

// ---------------- CSR aggregation, 512-dim bf16 -----------------------------------
__global__ __launch_bounds__(256) void agg_csr(
    const bf16* __restrict__ h, const int* __restrict__ offsets,
    const int* __restrict__ src, const float* __restrict__ dinv,
    const float* __restrict__ selfw, bf16* __restrict__ y, int n)
{
    int wave = threadIdx.x >> 6, lane = threadIdx.x & 63;
    int dst = blockIdx.x * 4 + wave;
    if (dst >= n) return;
    int s0 = offsets[dst], s1 = offsets[dst + 1];
    float di = dinv[dst], sw = selfw[dst];
    short8 hv = *(const short8*)(h + (size_t)dst * HDIM + lane * 8);
    float acc[8];
#pragma unroll
    for (int j = 0; j < 8; j++) acc[j] = sw * bf2f(hv[j]);
    for (int p = s0; p < s1; p++) {
        int sr = src[p];
        float nm = di * dinv[sr];
        short8 v = *(const short8*)(h + (size_t)sr * HDIM + lane * 8);
#pragma unroll
        for (int j = 0; j < 8; j++) acc[j] += nm * bf2f(v[j]);
    }
    short8 o;
#pragma unroll
    for (int j = 0; j < 8; j++) ((bf16*)&o)[j] = __float2bfloat16(acc[j]);
    *(short8*)(y + (size_t)dst * HDIM + lane * 8) = o;
}

// ---------------- BatchNorm stats + coeffs ---------------------------------------
__global__ __launch_bounds__(512) void bn_stats(
    const bf16* __restrict__ y, float* __restrict__ gsum, float* __restrict__ gsq, int n)
{
    int f = threadIdx.x;
    int per = (n + gridDim.x - 1) / gridDim.x;
    int r0 = blockIdx.x * per;
    int r1 = min(r0 + per, n);
    float s = 0.f, sq = 0.f;
    for (int rr = r0; rr < r1; rr++) {
        float v = bf2f(__builtin_bit_cast(short, y[(size_t)rr * HDIM + f]));
        s += v; sq += v * v;
    }
    atomicAdd(&gsum[f], s);
    atomicAdd(&gsq[f], sq);
}

__global__ void bn_final(const float* __restrict__ gsum, const float* __restrict__ gsq,
                         const void* __restrict__ gamma, const void* __restrict__ beta,
                         float* __restrict__ scale, float* __restrict__ shift,
                         float invN, const int* __restrict__ flags)
{
    int f = threadIdx.x;
    float g = flags[1] ? ((const float*)gamma)[f]
                       : __bfloat162float(((const bf16*)gamma)[f]);
    float b = flags[1] ? ((const float*)beta)[f]
                       : __bfloat162float(((const bf16*)beta)[f]);
    float mu = gsum[f] * invN;
    float var = fmaxf(gsq[f] * invN - mu * mu, 0.f);
    float inv = rsqrtf(var + BN_EPS);
    float sc = g * inv;
    scale[f] = sc;
    shift[f] = b - mu * sc;
}

// ---------------- pooling with fused BN+LeakyReLU (monotone) ----------------------
__global__ __launch_bounds__(512) void pool_fused(
    const bf16* __restrict__ y, const int* __restrict__ batch,
    const float* __restrict__ scale, const float* __restrict__ shift,
    bf16* __restrict__ pooled, int n)
{
    int g = blockIdx.x;
    int f = threadIdx.x;
    int lo = 0, hi = n;
    while (lo < hi) { int mid = (lo + hi) >> 1; if (batch[mid] < g) lo = mid + 1; else hi = mid; }
    int s = lo;
    hi = n;
    while (lo < hi) { int mid = (lo + hi) >> 1; if (batch[mid] <= g) lo = mid + 1; else hi = mid; }
    int e = lo;
    float mx = -3.0e38f, mn = 3.0e38f;
    for (int rr = s; rr < e; rr++) {
        float v = bf2f(__builtin_bit_cast(short, y[(size_t)rr * HDIM + f]));
        mx = fmaxf(mx, v); mn = fminf(mn, v);
    }
    float outv = 0.f;
    if (s < e) {
        float sc = scale[f];
        float t = sc * (sc >= 0.f ? mx : mn) + shift[f];
        outv = t > 0.f ? t : SLOPE * t;
    }
    pooled[(size_t)g * HDIM + f] = __float2bfloat16(outv);
}

// ---------------- orchestration --------------------------------------------------
extern "C" void kernel_launch(void* const* d_in, const int* in_sizes, int n_in,
                              void* d_out, int out_size, void* d_ws, size_t ws_size,
                              hipStream_t stream)
{
    const void* x     = d_in[0];
    const int*  ei    = (const int*)d_in[1];
    const int*  batch = (const int*)d_in[2];
    // d_in[4]=b1, d_in[8]=b2 cancel in training-mode BatchNorm — unused.

    const int N   = in_sizes[2];
    const int E   = in_sizes[1] / 2;
    const int DIN = 128;           // fixed by problem (in_sizes[0]/N)
    const int OUT = 256;
    const int G   = out_size / OUT;

    // workspace carve — ~236 MB
    char* p = (char*)d_ws;
    bf16* B1     = (bf16*)p;  p += (size_t)N * HDIM * sizeof(bf16);   // 102.4 MB
    bf16* B2     = (bf16*)p;  p += (size_t)N * HDIM * sizeof(bf16);   // 102.4 MB
    bf16* Q      = (bf16*)p;  p += (size_t)N * DIN * sizeof(bf16);    // 25.6 MB (aggx; later pooled)
    bf16* W1T    = (bf16*)p;  p += (size_t)HDIM * DIN * sizeof(bf16);
    bf16* W2T    = (bf16*)p;  p += (size_t)HDIM * HDIM * sizeof(bf16);
    bf16* WfT    = (bf16*)p;  p += (size_t)OUT * HDIM * sizeof(bf16);
    bf16* bfbf   = (bf16*)p;  p += 512 * sizeof(bf16);
    int* ei32    = (int*)p;   p += (size_t)2 * E * sizeof(int);
    int* batch32 = (int*)p;   p += (size_t)N * sizeof(int);
    float* dinv  = (float*)p; p += (size_t)N * sizeof(float);
    float* selfw = (float*)p; p += (size_t)N * sizeof(float);
    int* offsets = (int*)p;   p += (size_t)(N + 4) * sizeof(int);
    int* cursor  = (int*)p;   p += (size_t)N * sizeof(int);
    int* srcarr  = (int*)p;   p += (size_t)E * sizeof(int);
    float* gsum  = (float*)p; p += HDIM * sizeof(float);
    float* gsq   = (float*)p; p += HDIM * sizeof(float);
    float* sc1   = (float*)p; p += HDIM * sizeof(float);
    float* sh1   = (float*)p; p += HDIM * sizeof(float);
    float* sc2   = (float*)p; p += HDIM * sizeof(float);
    float* sh2   = (float*)p; p += HDIM * sizeof(float);
    int* flags   = (int*)p;   p += 4 * sizeof(int);

    // ---- dtype detection + canonicalization ----
    detect_types<<<1, 256, 0, stream>>>(ei, (const unsigned*)x, flags);
    conv_idx<<<(2 * E + 255) / 256, 256, 0, stream>>>(ei, ei32, 2 * E, flags);
    conv_idx<<<(N + 255) / 256, 256, 0, stream>>>(batch, batch32, N, flags);
    wt_conv<<<(DIN * HDIM + 255) / 256, 256, 0, stream>>>(d_in[3], W1T, DIN, HDIM, flags);
    wt_conv<<<(HDIM * HDIM + 255) / 256, 256, 0, stream>>>(d_in[7], W2T, HDIM, HDIM, flags);
    wt_conv<<<(HDIM * OUT + 255) / 256, 256, 0, stream>>>(d_in[11], WfT, HDIM, OUT, flags);
    conv_float<<<1, 256, 0, stream>>>(d_in[12], bfbf, OUT, flags);

    const int* rows = ei32;
    const int* cols = ei32 + E;

    // ---- CSR + degrees (shared by both conv layers) ----
    hipMemsetAsync(cursor, 0, (size_t)N * sizeof(int), stream);
    count_deg<<<(E + 255) / 256, 256, 0, stream>>>(cols, cursor, E);
    finalize_deg<<<(N + 255) / 256, 256, 0, stream>>>(cursor, dinv, selfw, N);
    scan_offsets<<<1, SCAN_T, 0, stream>>>(cursor, offsets, N, E);
    hipMemsetAsync(cursor, 0, (size_t)N * sizeof(int), stream);
    scatter_edges<<<(E + 255) / 256, 256, 0, stream>>>(rows, cols, offsets, cursor, srcarr, E);

    int strip_blocks = (N + 63) / 64;
    int agg_blocks = (N + 3) / 4;

    // ---- layer 1: aggregate x first (agg is linear), then GEMM ----
    agg_csr_din<<<agg_blocks, 256, 0, stream>>>(x, offsets, srcarr, dinv, selfw, Q, N, flags);
    gemm_nt<HDIM, false><<<strip_blocks, 256, 0, stream>>>(
        Q, W1T, B2, nullptr, nullptr, nullptr, N, DIN, nullptr);
    hipMemsetAsync(gsum, 0, 2 * HDIM * sizeof(float), stream);   // gsum+gsq contiguous
    bn_stats<<<256, HDIM, 0, stream>>>(B2, gsum, gsq, N);
    bn_final<<<1, HDIM, 0, stream>>>(gsum, gsq, d_in[5], d_in[6], sc1, sh1, 1.0f / N, flags);

    // ---- layer 2: GEMM with fused BN+leaky on A-load, then aggregate ----
    gemm_nt<HDIM, true><<<strip_blocks, 256, 0, stream>>>(
        B2, W2T, B1, nullptr, sc1, sh1, N, HDIM, nullptr);
    agg_csr<<<agg_blocks, 256, 0, stream>>>(B1, offsets, srcarr, dinv, selfw, B2, N);
    hipMemsetAsync(gsum, 0, 2 * HDIM * sizeof(float), stream);
    bn_stats<<<256, HDIM, 0, stream>>>(B2, gsum, gsq, N);
    bn_final<<<1, HDIM, 0, stream>>>(gsum, gsq, d_in[9], d_in[10], sc2, sh2, 1.0f / N, flags);

    // ---- pool (fused BN+leaky, monotone) + head GEMM ----
    pool_fused<<<G, HDIM, 0, stream>>>(B2, batch32, sc2, sh2, Q, N);
    gemm_nt<256, false><<<(G + 63) / 64, 256, 0, stream>>>(
        Q, WfT, d_out, bfbf, nullptr, nullptr, G, HDIM, flags + 1);
}

// Round 6
// 772.330 us; speedup vs baseline: 1.4257x; 1.1900x over previous
//
#include <hip/hip_runtime.h>
#include <hip/hip_bf16.h>

typedef __hip_bfloat16 bf16;
typedef __attribute__((ext_vector_type(8))) short short8;
typedef __attribute__((ext_vector_type(4))) float f32x4;

#define HDIM 512
#define SLOPE 0.01f
#define BN_EPS 1e-5f

__device__ inline float bf2f(short s) {
    unsigned u = ((unsigned)(unsigned short)s) << 16;
    return __builtin_bit_cast(float, u);
}
__device__ inline unsigned short f2bfbits(float v) {
    bf16 h = __float2bfloat16(v);
    return (unsigned short)__builtin_bit_cast(short, h);
}

// ---------------- runtime dtype detection ----------------
// flags[0]=1 if indices int64; flags[1]=1 if float tensors fp32.
__global__ void detect_types(const int* __restrict__ ei, const unsigned* __restrict__ xw,
                             int* __restrict__ flags) {
    __shared__ int nzhi, okbf;
    if (threadIdx.x == 0) { nzhi = 0; okbf = 0; }
    __syncthreads();
    int lo = 0, ok = 0;
    for (int i = threadIdx.x; i < 2048; i += 256)
        if (ei[2 * i + 1] != 0) lo++;
    for (int i = threadIdx.x; i < 1024; i += 256) {
        unsigned w = (xw[i] & 0xFFFFu) << 16;
        float av = fabsf(__builtin_bit_cast(float, w));
        if (av > 0.0009f && av < 64.0f) ok++;
    }
    if (lo) atomicAdd(&nzhi, lo);
    if (ok) atomicAdd(&okbf, ok);
    __syncthreads();
    if (threadIdx.x == 0) {
        flags[0] = (nzhi == 0) ? 1 : 0;
        flags[1] = (okbf < 512) ? 1 : 0;
    }
}

__global__ void conv_idx(const int* __restrict__ src, int* __restrict__ dst, int n,
                         const int* __restrict__ flags) {
    int i = blockIdx.x * blockDim.x + threadIdx.x;
    if (i < n) dst[i] = flags[0] ? (int)((const long long*)src)[i] : src[i];
}

__global__ void conv_float(const void* __restrict__ src, bf16* __restrict__ dst, int n,
                           const int* __restrict__ flags) {
    int i = blockIdx.x * blockDim.x + threadIdx.x;
    if (i < n)
        dst[i] = flags[1] ? __float2bfloat16(((const float*)src)[i])
                          : ((const bf16*)src)[i];
}

// transpose + convert weight: WT[nn][k] = W[k][nn]  (W is [K][Nn])
__global__ void wt_conv(const void* __restrict__ W, bf16* __restrict__ WT,
                        int K, int Nn, const int* __restrict__ flags) {
    int idx = blockIdx.x * 256 + threadIdx.x;
    if (idx >= K * Nn) return;
    int nn = idx / K;
    int k = idx - nn * K;
    float v = flags[1] ? ((const float*)W)[(size_t)k * Nn + nn]
                       : __bfloat162float(((const bf16*)W)[(size_t)k * Nn + nn]);
    WT[idx] = __float2bfloat16(v);
}

// ---------------- degree + CSR build ----------------
__global__ void count_deg(const int* __restrict__ col, int* __restrict__ cnt, int e) {
    int i = blockIdx.x * blockDim.x + threadIdx.x;
    if (i < e) atomicAdd(&cnt[col[i]], 1);
}

__global__ void finalize_deg(const int* __restrict__ cnt, float* __restrict__ dinv,
                             float* __restrict__ selfw, int n) {
    int i = blockIdx.x * blockDim.x + threadIdx.x;
    if (i < n) {
        float d = (float)cnt[i] + 2.0f;
        dinv[i] = rsqrtf(d);
        selfw[i] = 2.0f / d;
    }
}

// ---------------- parallel exclusive scan (3 kernels, 512 elems/block) -----------
__global__ __launch_bounds__(256) void scan_part(
    const int* __restrict__ counts, int* __restrict__ offsets,
    int* __restrict__ bsum, int n)
{
    __shared__ int s[512];
    int b = blockIdx.x;
    int base = b * 512;
    int t = threadIdx.x;
    s[t]       = (base + t       < n) ? counts[base + t]       : 0;
    s[t + 256] = (base + t + 256 < n) ? counts[base + t + 256] : 0;

    // Blelloch up-sweep
    int offset = 1;
    for (int d = 256; d > 0; d >>= 1) {
        __syncthreads();
        if (t < d) {
            int ai = offset * (2 * t + 1) - 1;
            int bi = offset * (2 * t + 2) - 1;
            s[bi] += s[ai];
        }
        offset <<= 1;
    }
    __syncthreads();
    if (t == 0) { bsum[b] = s[511]; s[511] = 0; }
    // down-sweep
    for (int d = 1; d < 512; d <<= 1) {
        offset >>= 1;
        __syncthreads();
        if (t < d) {
            int ai = offset * (2 * t + 1) - 1;
            int bi = offset * (2 * t + 2) - 1;
            int tmp = s[ai]; s[ai] = s[bi]; s[bi] += tmp;
        }
    }
    __syncthreads();
    if (base + t < n)       offsets[base + t]       = s[t];
    if (base + t + 256 < n) offsets[base + t + 256] = s[t + 256];
}

__global__ __launch_bounds__(1024) void scan_tops(int* __restrict__ bsum, int nb) {
    __shared__ int s[1024];
    int t = threadIdx.x;
    s[t] = (t < nb) ? bsum[t] : 0;
    __syncthreads();
    for (int off = 1; off < 1024; off <<= 1) {
        int v = (t >= off) ? s[t - off] : 0;
        __syncthreads();
        s[t] += v;
        __syncthreads();
    }
    if (t < nb) bsum[t] = (t == 0) ? 0 : s[t - 1];   // exclusive
}

__global__ __launch_bounds__(256) void scan_add(
    int* __restrict__ offsets, const int* __restrict__ bsum, int n, int e)
{
    int b = blockIdx.x;
    int base = b * 512;
    int add = bsum[b];
    int t = threadIdx.x;
    if (base + t < n)       offsets[base + t]       += add;
    if (base + t + 256 < n) offsets[base + t + 256] += add;
    if (b == 0 && t == 0) offsets[n] = e;
}

__global__ void scatter_edges(const int* __restrict__ rows, const int* __restrict__ cols,
                              const int* __restrict__ offsets, int* __restrict__ cursor,
                              int* __restrict__ src, int e)
{
    int i = blockIdx.x * blockDim.x + threadIdx.x;
    if (i < e) {
        int d = cols[i];
        int pos = offsets[d] + atomicAdd(&cursor[d], 1);
        src[pos] = rows[i];
    }
}

// ---------------- full-width GEMM: C[M,NT] = A[M,K] @ BT^T, strips of 64 rows -----
// BT is pre-transposed [NT][K]. APPLY: A-elements get leaky(scale*a+shift) on load.
template<int NT, bool APPLY>
__global__ __launch_bounds__(256, 2) void gemm_nt(
    const bf16* __restrict__ A, const bf16* __restrict__ BT,
    void* __restrict__ C, const bf16* __restrict__ bias,
    const float* __restrict__ scale, const float* __restrict__ shift,
    int M, int K, const int* __restrict__ cf32)
{
    constexpr int NI = NT / 64;          // 16-wide n-tiles per wave
    __shared__ bf16 As[64][40];          // stride 40: frag reads conflict-free
    __shared__ bf16 Bs[NT][40];
    __shared__ float s_sc[APPLY ? HDIM : 1];
    __shared__ float s_sh[APPLY ? HDIM : 1];

    int tid = threadIdx.x;
    int wave = tid >> 6, lane = tid & 63, q = lane >> 4, r = lane & 15;
    int m0 = blockIdx.x * 64;
    int rr = tid >> 2, kk = (tid & 3) * 8;
    bool c32 = cf32 && *cf32;

    if constexpr (APPLY) {
        for (int i = tid; i < K; i += 256) { s_sc[i] = scale[i]; s_sh[i] = shift[i]; }
    }
    __syncthreads();

    f32x4 acc[4][NI];
#pragma unroll
    for (int mi = 0; mi < 4; mi++)
#pragma unroll
        for (int ni = 0; ni < NI; ni++)
            acc[mi][ni] = {0.f, 0.f, 0.f, 0.f};

    int gm = m0 + rr;
    const bf16* Arow = A + (size_t)gm * K + kk;

    for (int k0 = 0; k0 < K; k0 += 32) {
        short8 v = {0, 0, 0, 0, 0, 0, 0, 0};
        if (gm < M) v = *(const short8*)(Arow + k0);
        if constexpr (APPLY) {
            f32x4 sca = *(const f32x4*)&s_sc[k0 + kk];
            f32x4 scb = *(const f32x4*)&s_sc[k0 + kk + 4];
            f32x4 sha = *(const f32x4*)&s_sh[k0 + kk];
            f32x4 shb = *(const f32x4*)&s_sh[k0 + kk + 4];
#pragma unroll
            for (int j = 0; j < 4; j++) {
                float t = sca[j] * bf2f(v[j]) + sha[j];
                v[j] = __builtin_bit_cast(short, (short)f2bfbits(t > 0.f ? t : SLOPE * t));
                float u = scb[j] * bf2f(v[4 + j]) + shb[j];
                v[4 + j] = __builtin_bit_cast(short, (short)f2bfbits(u > 0.f ? u : SLOPE * u));
            }
        }
        *(short8*)&As[rr][kk] = v;
#pragma unroll
        for (int p = 0; p < NT / 64; p++) {
            int n = p * 64 + rr;
            *(short8*)&Bs[n][kk] = *(const short8*)(BT + (size_t)n * K + k0 + kk);
        }
        __syncthreads();

        short8 a[4];
#pragma unroll
        for (int mi = 0; mi < 4; mi++) a[mi] = *(const short8*)&As[mi * 16 + r][q * 8];
#pragma unroll
        for (int ni = 0; ni < NI; ni++) {
            short8 b = *(const short8*)&Bs[wave * (NT / 4) + ni * 16 + r][q * 8];
#pragma unroll
            for (int mi = 0; mi < 4; mi++)
                acc[mi][ni] = __builtin_amdgcn_mfma_f32_16x16x32_bf16(a[mi], b, acc[mi][ni], 0, 0, 0);
        }
        __syncthreads();
    }

#pragma unroll
    for (int mi = 0; mi < 4; mi++) {
#pragma unroll
        for (int ni = 0; ni < NI; ni++) {
            int gn = wave * (NT / 4) + ni * 16 + r;
            float bv = bias ? __bfloat162float(bias[gn]) : 0.f;
#pragma unroll
            for (int reg = 0; reg < 4; reg++) {
                int gm2 = m0 + mi * 16 + q * 4 + reg;
                if (gm2 < M) {
                    float val = acc[mi][ni][reg] + bv;
                    if (c32) ((float*)C)[(size_t)gm2 * NT + gn] = val;
                    else     ((bf16*)C)[(size_t)gm2 * NT + gn] = __float2bfloat16(val);
                }
            }
        }
    }
}

// ---------------- CSR aggregation, 128-dim input (fp32 or bf16 x) -----------------
__global__ __launch_bounds__(256) void agg_csr_din(
    const void* __restrict__ x, const int* __restrict__ offsets,
    const int* __restrict__ src, const float* __restrict__ dinv,
    const float* __restrict__ selfw, bf16* __restrict__ out,
    int n, const int* __restrict__ flags)
{
    int wave = threadIdx.x >> 6, lane = threadIdx.x & 63;
    int dst = blockIdx.x * 4 + wave;
    if (dst >= n) return;
    bool f32 = flags[1] != 0;
    int s0 = offsets[dst], s1 = offsets[dst + 1];
    float di = dinv[dst], sw = selfw[dst];
    float a0, a1;
    if (f32) {
        float2 v = ((const float2*)x)[(size_t)dst * 64 + lane];
        a0 = sw * v.x; a1 = sw * v.y;
    } else {
        unsigned u = ((const unsigned*)x)[(size_t)dst * 64 + lane];
        a0 = sw * bf2f((short)(u & 0xFFFF)); a1 = sw * bf2f((short)(u >> 16));
    }
    for (int p = s0; p < s1; p++) {
        int sr = src[p];
        float nm = di * dinv[sr];
        if (f32) {
            float2 v = ((const float2*)x)[(size_t)sr * 64 + lane];
            a0 += nm * v.x; a1 += nm * v.y;
        } else {
            unsigned u = ((const unsigned*)x)[(size_t)sr * 64 + lane];
            a0 += nm * bf2f((short)(u & 0xFFFF)); a1 += nm * bf2f((short)(u >> 16));
        }
    }
    unsigned o = (unsigned)f2bfbits(a0) | ((unsigned)f2bfbits(a1) << 16);
    ((unsigned*)out)[(size_t)dst * 64 + lane] = o;
}

// ---------------- CSR aggregation, 512-dim bf16 -----------------------------------
__global__ __launch_bounds__(256) void agg_csr(
    const bf16* __restrict__ h, const int* __restrict__ offsets,
    const int* __restrict__ src, const float* __restrict__ dinv,
    const float* __restrict__ selfw, bf16* __restrict__ y, int n)
{
    int wave = threadIdx.x >> 6, lane = threadIdx.x & 63;
    int dst = blockIdx.x * 4 + wave;
    if (dst >= n) return;
    int s0 = offsets[dst], s1 = offsets[dst + 1];
    float di = dinv[dst], sw = selfw[dst];
    short8 hv = *(const short8*)(h + (size_t)dst * HDIM + lane * 8);
    float acc[8];
#pragma unroll
    for (int j = 0; j < 8; j++) acc[j] = sw * bf2f(hv[j]);
    for (int p = s0; p < s1; p++) {
        int sr = src[p];
        float nm = di * dinv[sr];
        short8 v = *(const short8*)(h + (size_t)sr * HDIM + lane * 8);
#pragma unroll
        for (int j = 0; j < 8; j++) acc[j] += nm * bf2f(v[j]);
    }
    short8 o;
#pragma unroll
    for (int j = 0; j < 8; j++) ((bf16*)&o)[j] = __float2bfloat16(acc[j]);
    *(short8*)(y + (size_t)dst * HDIM + lane * 8) = o;
}

// ---------------- BatchNorm stats + coeffs ---------------------------------------
__global__ __launch_bounds__(512) void bn_stats(
    const bf16* __restrict__ y, float* __restrict__ gsum, float* __restrict__ gsq, int n)
{
    int f = threadIdx.x;
    int per = (n + gridDim.x - 1) / gridDim.x;
    int r0 = blockIdx.x * per;
    int r1 = min(r0 + per, n);
    float s = 0.f, sq = 0.f;
    for (int rr = r0; rr < r1; rr++) {
        float v = bf2f(__builtin_bit_cast(short, y[(size_t)rr * HDIM + f]));
        s += v; sq += v * v;
    }
    atomicAdd(&gsum[f], s);
    atomicAdd(&gsq[f], sq);
}

__global__ void bn_final(const float* __restrict__ gsum, const float* __restrict__ gsq,
                         const void* __restrict__ gamma, const void* __restrict__ beta,
                         float* __restrict__ scale, float* __restrict__ shift,
                         float invN, const int* __restrict__ flags)
{
    int f = threadIdx.x;
    float g = flags[1] ? ((const float*)gamma)[f]
                       : __bfloat162float(((const bf16*)gamma)[f]);
    float b = flags[1] ? ((const float*)beta)[f]
                       : __bfloat162float(((const bf16*)beta)[f]);
    float mu = gsum[f] * invN;
    float var = fmaxf(gsq[f] * invN - mu * mu, 0.f);
    float inv = rsqrtf(var + BN_EPS);
    float sc = g * inv;
    scale[f] = sc;
    shift[f] = b - mu * sc;
}

// ---------------- pooling with fused BN+LeakyReLU (monotone) ----------------------
__global__ __launch_bounds__(512) void pool_fused(
    const bf16* __restrict__ y, const int* __restrict__ batch,
    const float* __restrict__ scale, const float* __restrict__ shift,
    bf16* __restrict__ pooled, int n)
{
    int g = blockIdx.x;
    int f = threadIdx.x;
    int lo = 0, hi = n;
    while (lo < hi) { int mid = (lo + hi) >> 1; if (batch[mid] < g) lo = mid + 1; else hi = mid; }
    int s = lo;
    hi = n;
    while (lo < hi) { int mid = (lo + hi) >> 1; if (batch[mid] <= g) lo = mid + 1; else hi = mid; }
    int e = lo;
    float mx = -3.0e38f, mn = 3.0e38f;
    for (int rr = s; rr < e; rr++) {
        float v = bf2f(__builtin_bit_cast(short, y[(size_t)rr * HDIM + f]));
        mx = fmaxf(mx, v); mn = fminf(mn, v);
    }
    float outv = 0.f;
    if (s < e) {
        float sc = scale[f];
        float t = sc * (sc >= 0.f ? mx : mn) + shift[f];
        outv = t > 0.f ? t : SLOPE * t;
    }
    pooled[(size_t)g * HDIM + f] = __float2bfloat16(outv);
}

// ---------------- orchestration --------------------------------------------------
extern "C" void kernel_launch(void* const* d_in, const int* in_sizes, int n_in,
                              void* d_out, int out_size, void* d_ws, size_t ws_size,
                              hipStream_t stream)
{
    const void* x     = d_in[0];
    const int*  ei    = (const int*)d_in[1];
    const int*  batch = (const int*)d_in[2];
    // d_in[4]=b1, d_in[8]=b2 cancel in training-mode BatchNorm — unused.

    const int N   = in_sizes[2];
    const int E   = in_sizes[1] / 2;
    const int DIN = 128;
    const int OUT = 256;
    const int G   = out_size / OUT;

    // workspace carve — ~236 MB
    char* p = (char*)d_ws;
    bf16* B1     = (bf16*)p;  p += (size_t)N * HDIM * sizeof(bf16);   // 102.4 MB
    bf16* B2     = (bf16*)p;  p += (size_t)N * HDIM * sizeof(bf16);   // 102.4 MB
    bf16* Q      = (bf16*)p;  p += (size_t)N * DIN * sizeof(bf16);    // 25.6 MB (aggx; later pooled)
    bf16* W1T    = (bf16*)p;  p += (size_t)HDIM * DIN * sizeof(bf16);
    bf16* W2T    = (bf16*)p;  p += (size_t)HDIM * HDIM * sizeof(bf16);
    bf16* WfT    = (bf16*)p;  p += (size_t)OUT * HDIM * sizeof(bf16);
    bf16* bfbf   = (bf16*)p;  p += 512 * sizeof(bf16);
    int* ei32    = (int*)p;   p += (size_t)2 * E * sizeof(int);
    int* batch32 = (int*)p;   p += (size_t)N * sizeof(int);
    float* dinv  = (float*)p; p += (size_t)N * sizeof(float);
    float* selfw = (float*)p; p += (size_t)N * sizeof(float);
    int* offsets = (int*)p;   p += (size_t)(N + 4) * sizeof(int);
    int* cursor  = (int*)p;   p += (size_t)N * sizeof(int);
    int* srcarr  = (int*)p;   p += (size_t)E * sizeof(int);
    int* bsum    = (int*)p;   p += 1024 * sizeof(int);
    float* gsum  = (float*)p; p += HDIM * sizeof(float);
    float* gsq   = (float*)p; p += HDIM * sizeof(float);
    float* sc1   = (float*)p; p += HDIM * sizeof(float);
    float* sh1   = (float*)p; p += HDIM * sizeof(float);
    float* sc2   = (float*)p; p += HDIM * sizeof(float);
    float* sh2   = (float*)p; p += HDIM * sizeof(float);
    int* flags   = (int*)p;   p += 4 * sizeof(int);

    // ---- dtype detection + canonicalization ----
    detect_types<<<1, 256, 0, stream>>>(ei, (const unsigned*)x, flags);
    conv_idx<<<(2 * E + 255) / 256, 256, 0, stream>>>(ei, ei32, 2 * E, flags);
    conv_idx<<<(N + 255) / 256, 256, 0, stream>>>(batch, batch32, N, flags);
    wt_conv<<<(DIN * HDIM + 255) / 256, 256, 0, stream>>>(d_in[3], W1T, DIN, HDIM, flags);
    wt_conv<<<(HDIM * HDIM + 255) / 256, 256, 0, stream>>>(d_in[7], W2T, HDIM, HDIM, flags);
    wt_conv<<<(HDIM * OUT + 255) / 256, 256, 0, stream>>>(d_in[11], WfT, HDIM, OUT, flags);
    conv_float<<<1, 256, 0, stream>>>(d_in[12], bfbf, OUT, flags);

    const int* rows = ei32;
    const int* cols = ei32 + E;

    // ---- CSR + degrees (shared by both conv layers) ----
    hipMemsetAsync(cursor, 0, (size_t)N * sizeof(int), stream);
    count_deg<<<(E + 255) / 256, 256, 0, stream>>>(cols, cursor, E);
    finalize_deg<<<(N + 255) / 256, 256, 0, stream>>>(cursor, dinv, selfw, N);
    int nb = (N + 511) / 512;
    scan_part<<<nb, 256, 0, stream>>>(cursor, offsets, bsum, N);
    scan_tops<<<1, 1024, 0, stream>>>(bsum, nb);
    scan_add<<<nb, 256, 0, stream>>>(offsets, bsum, N, E);
    hipMemsetAsync(cursor, 0, (size_t)N * sizeof(int), stream);
    scatter_edges<<<(E + 255) / 256, 256, 0, stream>>>(rows, cols, offsets, cursor, srcarr, E);

    int strip_blocks = (N + 63) / 64;
    int agg_blocks = (N + 3) / 4;

    // ---- layer 1: aggregate x first (agg is linear), then GEMM ----
    agg_csr_din<<<agg_blocks, 256, 0, stream>>>(x, offsets, srcarr, dinv, selfw, Q, N, flags);
    gemm_nt<HDIM, false><<<strip_blocks, 256, 0, stream>>>(
        Q, W1T, B2, nullptr, nullptr, nullptr, N, DIN, nullptr);
    hipMemsetAsync(gsum, 0, 2 * HDIM * sizeof(float), stream);   // gsum+gsq contiguous
    bn_stats<<<256, HDIM, 0, stream>>>(B2, gsum, gsq, N);
    bn_final<<<1, HDIM, 0, stream>>>(gsum, gsq, d_in[5], d_in[6], sc1, sh1, 1.0f / N, flags);

    // ---- layer 2: GEMM with fused BN+leaky on A-load, then aggregate ----
    gemm_nt<HDIM, true><<<strip_blocks, 256, 0, stream>>>(
        B2, W2T, B1, nullptr, sc1, sh1, N, HDIM, nullptr);
    agg_csr<<<agg_blocks, 256, 0, stream>>>(B1, offsets, srcarr, dinv, selfw, B2, N);
    hipMemsetAsync(gsum, 0, 2 * HDIM * sizeof(float), stream);
    bn_stats<<<256, HDIM, 0, stream>>>(B2, gsum, gsq, N);
    bn_final<<<1, HDIM, 0, stream>>>(gsum, gsq, d_in[9], d_in[10], sc2, sh2, 1.0f / N, flags);

    // ---- pool (fused BN+leaky, monotone) + head GEMM ----
    pool_fused<<<G, HDIM, 0, stream>>>(B2, batch32, sc2, sh2, Q, N);
    gemm_nt<256, false><<<(G + 63) / 64, 256, 0, stream>>>(
        Q, WfT, d_out, bfbf, nullptr, nullptr, G, HDIM, flags + 1);
}